// Round 9
// baseline (392.062 us; speedup 1.0000x reference)
//
#include <hip/hip_runtime.h>

// TemplatePointwiseAttention, MI355X/gfx950.
// Folded-weight formulation: G = Z @ Abar (MFMA), 4-way softmax, OUT = S @ Mbar.
// R9: fix the register-prefetch contradiction R8 exposed (named live prefetch
// state 128 regs > VGPR_Count 120 -> compiler sank the prefetches; latency
// exposed at 2 waves/SIMD). Two changes:
//  (a) PHASE-LOCAL prefetch: zb lives only in X (issued X-top, covered by G2);
//      kt lives only in Y (issued X-end, crosses one barrier). Peak ~110 regs.
//  (b) 4 waves/SIMD: one 1024-thread persistent block per CU (16 waves),
//      PB=64, NT=9 (half the barriers). __launch_bounds__(1024,4) makes the
//      <=128 VGPR contract explicit (mandatory for a 1024-thread block).
// LDS: sAbar 64K + sG 2x32K = 128 KB. Barriers stay {lgkmcnt(0); s_barrier}.

#define R_    384
#define P_    (R_ * R_)      // 147456 residue pairs
#define PB    64             // pairs per tile
#define NPB   256            // persistent blocks = CUs
#define NT_   9              // tiles per block

typedef __attribute__((ext_vector_type(8))) short  short8;   // 8 x bf16 MFMA frag
typedef __attribute__((ext_vector_type(4))) float  f32x4;    // MFMA accumulator

union S8U { short8 s8; unsigned u[4]; };

__device__ __forceinline__ unsigned short f2bf(float f) {
  unsigned u = __float_as_uint(f);
  unsigned r = ((u >> 16) & 1u) + 0x7FFFu;   // RNE
  return (unsigned short)((u + r) >> 16);
}
__device__ __forceinline__ float bf2f(unsigned short s) {
  return __uint_as_float(((unsigned)s) << 16);
}
__device__ __forceinline__ unsigned cvtpk(float lo, float hi) {
  unsigned d;
  asm("v_cvt_pk_bf16_f32 %0, %1, %2" : "=v"(d) : "v"(lo), "v"(hi));
  return d;
}
// bf16 LDS tiles [p][c] (p<64, c<256), pitch 256, XOR-swizzled in 16B blocks.
__device__ __forceinline__ int swz(int p, int c) {
  return p * 256 + ((((c >> 3) ^ (p & 31)) << 3) | (c & 7));
}
#define SB() __builtin_amdgcn_sched_barrier(0)
// Raw barrier: LDS drain only — in-flight VMEM (kt prefetch) crosses it.
#define BAR() do { \
    asm volatile("s_waitcnt lgkmcnt(0)\ns_barrier" ::: "memory"); \
    SB(); \
  } while (0)

// ---- K0: fold weights into AbarT[n=256][i=128], MbarT[o=128][k=256] (bf16) ----
__global__ void prep_kernel(const float* __restrict__ Wq, const float* __restrict__ Wk,
                            const float* __restrict__ Wv, const float* __restrict__ Wo,
                            unsigned short* __restrict__ AbarT,
                            unsigned short* __restrict__ MbarT) {
  int tid = blockIdx.x * blockDim.x + threadIdx.x;   // 65536 threads
  if (tid < 256 * 128) {
    int n = tid >> 7, i = tid & 127;
    int h = n >> 6, j = n & 63;
    const float* wq = Wq + i * 256 + h * 64;
    const float* wk = Wk + j * 256 + h * 64;
    float acc = 0.f;
#pragma unroll 8
    for (int c = 0; c < 64; ++c) acc += wq[c] * wk[c];
    AbarT[n * 128 + i] = f2bf(acc * 0.125f);         // 1/sqrt(64) folded in
  } else {
    int t2 = tid - 256 * 128;
    int o = t2 >> 8, k = t2 & 255;
    int h = k >> 6, j = k & 63;
    const float* wv = Wv + j * 256 + h * 64;
    const float* wo = Wo + (h * 64) * 128 + o;
    float acc = 0.f;
#pragma unroll 8
    for (int c = 0; c < 64; ++c) acc += wv[c] * wo[c * 128];
    MbarT[o * 256 + k] = f2bf(acc);
  }
}

// ---- persistent fused kernel: 1024 threads, 16 waves, 1 block/CU ----
__global__ __launch_bounds__(1024, 4) void attn_kernel(
    const float* __restrict__ z2d, const float* __restrict__ t2d,
    const unsigned short* __restrict__ AbarT, const unsigned short* __restrict__ MbarT,
    const float* __restrict__ bo, float* __restrict__ out) {
  extern __shared__ char smem[];
  unsigned short* sAbar = (unsigned short*)smem;           // 64 KB bf16 swizzled
  unsigned short* sG    = (unsigned short*)(smem + 65536); // 2 x [64][256] bf16 swz

  const int tid  = threadIdx.x;
  const int wv_  = tid >> 6;
  const int lane = tid & 63;
  const int l = lane & 15;     // MFMA: A row / B col / D col
  const int q = lane >> 4;     // MFMA quad
  const int mt = wv_ & 3;      // m-tile (16 rows of 64)
  const int ng = wv_ >> 2;     // n-group (head for G1; o-group for G2)

  // ---- attention geometry: thread = (pair ap, head ah, quarter au) ----
  const int ap = tid >> 4;               // 0..63
  const int ah = (tid >> 2) & 3;
  const int au = tid & 3;
  const int aoG0 = swz(ap, ah * 64 + au * 16);
  const int aoG1 = swz(ap, ah * 64 + au * 16 + 8);

  const int p2g = mt * 16 + l;           // GEMM2 A-row (0..63)

  // ---- prologue: Abar -> LDS (swizzled); Mbar -> regs ----
#pragma unroll
  for (int k2 = 0; k2 < 4; ++k2) {
    int id = k2 * 1024 + tid, n = id >> 4, blk = id & 15;
    short8 v = *(const short8*)(AbarT + n * 128 + blk * 8);
    *(short8*)(sAbar + n * 128 + ((blk ^ (n & 15)) << 3)) = v;
  }
  short8 mb0[8], mb1[8];       // Mbar o-slices: o = ng*32 + {l, 16+l}
#pragma unroll
  for (int kk = 0; kk < 8; ++kk) {
    mb0[kk] = *(const short8*)(MbarT + (size_t)(ng * 32 + l) * 256 + kk * 32 + q * 8);
    mb1[kk] = *(const short8*)(MbarT + (size_t)(ng * 32 + 16 + l) * 256 + kk * 32 + q * 8);
  }
  const float bo0 = bo[ng * 32 + l];
  const float bo1 = bo[ng * 32 + 16 + l];
  BAR();   // sAbar visible

#pragma unroll 1
  for (int k = 0; k < NT_; ++k) {
    const int sl = k & 1;
    const size_t P0 = (size_t)(blockIdx.x + (size_t)k * NPB) * PB;

    // ======== phase X ========
    // (0) issue zb(k) — consumed by G1 below; G2's ~700cy covers the latency.
    float4 zb[8];
    {
      const float* zr = z2d + (P0 + (size_t)(mt * 16 + l)) * 128;
#pragma unroll
      for (int kk = 0; kk < 4; ++kk) {
        zb[2 * kk]     = *(const float4*)(zr + kk * 32 + q * 8);
        zb[2 * kk + 1] = *(const float4*)(zr + kk * 32 + q * 8 + 4);
      }
    }
    SB();
    // (1) GEMM2 tile k-1: S(sG[sl^1]) @ Mbar(regs) -> out
    if (k > 0) {
      const unsigned short* sGp = sG + (sl ^ 1) * 16384;
      f32x4 a20 = f32x4{0.f, 0.f, 0.f, 0.f};
      f32x4 a21 = f32x4{0.f, 0.f, 0.f, 0.f};
#pragma unroll
      for (int kk = 0; kk < 8; ++kk) {
        short8 af2 = *(const short8*)(sGp + p2g * 256 + (((kk * 4 + q) ^ (p2g & 31)) << 3));
        a20 = __builtin_amdgcn_mfma_f32_16x16x32_bf16(af2, mb0[kk], a20, 0, 0, 0);
        a21 = __builtin_amdgcn_mfma_f32_16x16x32_bf16(af2, mb1[kk], a21, 0, 0, 0);
      }
      const size_t rb = (P0 - (size_t)NPB * PB + (size_t)(mt * 16 + q * 4)) * 128;
#pragma unroll
      for (int r = 0; r < 4; ++r) {
        out[rb + r * 128 + ng * 32 + l]      = a20[r] + bo0;
        out[rb + r * 128 + ng * 32 + 16 + l] = a21[r] + bo1;
      }
    }
    SB();
    // (2) GEMM1 tile k: af=cvt(zb); B from sAbar; G -> sG[sl]. zb dies here.
    {
      f32x4 a1[4];
#pragma unroll
      for (int i = 0; i < 4; ++i) a1[i] = f32x4{0.f, 0.f, 0.f, 0.f};
#pragma unroll
      for (int kk = 0; kk < 4; ++kk) {
        S8U af;
        af.u[0] = cvtpk(zb[2 * kk].x,     zb[2 * kk].y);
        af.u[1] = cvtpk(zb[2 * kk].z,     zb[2 * kk].w);
        af.u[2] = cvtpk(zb[2 * kk + 1].x, zb[2 * kk + 1].y);
        af.u[3] = cvtpk(zb[2 * kk + 1].z, zb[2 * kk + 1].w);
#pragma unroll
        for (int i = 0; i < 4; ++i) {
          const int n = (ng * 4 + i) * 16 + l;
          short8 bf = *(const short8*)(sAbar + n * 128 + (((kk * 4 + q) ^ l) << 3));
          a1[i] = __builtin_amdgcn_mfma_f32_16x16x32_bf16(af.s8, bf, a1[i], 0, 0, 0);
        }
      }
      unsigned short* sGc = sG + sl * 16384;
#pragma unroll
      for (int i = 0; i < 4; ++i) {
        const int c = (ng * 4 + i) * 16 + l;
#pragma unroll
        for (int r = 0; r < 4; ++r)
          sGc[swz(mt * 16 + q * 4 + r, c)] = f2bf(a1[i][r]);  // m89-verified D layout
      }
    }
    SB();
    // (3) issue kt(k) — lives only through Y(k); crosses one barrier.
    float4 kt[4][4];   // kt[t][j]: t2d[t][P0+ap][au*16 + 4j .. +4)
    {
      const float* kb = t2d + (P0 + ap) * 64 + au * 16;
#pragma unroll
      for (int t = 0; t < 4; ++t)
#pragma unroll
        for (int j = 0; j < 4; ++j)
          kt[t][j] = *(const float4*)(kb + (size_t)t * (P_ * 64) + 4 * j);
    }
    SB();
    BAR();

    // ======== phase Y: attention (K in regs; S-pass reuses them) ========
    {
      unsigned short* sGc = sG + sl * 16384;
      short8 g0 = *(const short8*)(sGc + aoG0);
      short8 g1 = *(const short8*)(sGc + aoG1);
      float lg0 = 0.f, lg1 = 0.f, lg2 = 0.f, lg3 = 0.f;
#pragma unroll
      for (int j = 0; j < 4; ++j) {
        const float ga = bf2f((unsigned short)((j < 2) ? g0[4 * j]     : g1[4 * (j - 2)]));
        const float gb = bf2f((unsigned short)((j < 2) ? g0[4 * j + 1] : g1[4 * (j - 2) + 1]));
        const float gc = bf2f((unsigned short)((j < 2) ? g0[4 * j + 2] : g1[4 * (j - 2) + 2]));
        const float gd = bf2f((unsigned short)((j < 2) ? g0[4 * j + 3] : g1[4 * (j - 2) + 3]));
        lg0 += ga * kt[0][j].x + gb * kt[0][j].y + gc * kt[0][j].z + gd * kt[0][j].w;
        lg1 += ga * kt[1][j].x + gb * kt[1][j].y + gc * kt[1][j].z + gd * kt[1][j].w;
        lg2 += ga * kt[2][j].x + gb * kt[2][j].y + gc * kt[2][j].z + gd * kt[2][j].w;
        lg3 += ga * kt[3][j].x + gb * kt[3][j].y + gc * kt[3][j].z + gd * kt[3][j].w;
      }
      lg0 += __shfl_xor(lg0, 1); lg0 += __shfl_xor(lg0, 2);
      lg1 += __shfl_xor(lg1, 1); lg1 += __shfl_xor(lg1, 2);
      lg2 += __shfl_xor(lg2, 1); lg2 += __shfl_xor(lg2, 2);
      lg3 += __shfl_xor(lg3, 1); lg3 += __shfl_xor(lg3, 2);
      const float mx = fmaxf(fmaxf(lg0, lg1), fmaxf(lg2, lg3));
      float e0 = __expf(lg0 - mx), e1 = __expf(lg1 - mx);
      float e2 = __expf(lg2 - mx), e3 = __expf(lg3 - mx);
      const float inv = 1.f / (e0 + e1 + e2 + e3);
      e0 *= inv; e1 *= inv; e2 *= inv; e3 *= inv;
      // S[ap][ah*64+au*16+4j..+4) = sum_t e_t * K_t — straight from registers
#pragma unroll
      for (int j = 0; j < 4; ++j) {
        float s0 = e0 * kt[0][j].x + e1 * kt[1][j].x + e2 * kt[2][j].x + e3 * kt[3][j].x;
        float s1 = e0 * kt[0][j].y + e1 * kt[1][j].y + e2 * kt[2][j].y + e3 * kt[3][j].y;
        float s2 = e0 * kt[0][j].z + e1 * kt[1][j].z + e2 * kt[2][j].z + e3 * kt[3][j].z;
        float s3 = e0 * kt[0][j].w + e1 * kt[1][j].w + e2 * kt[2][j].w + e3 * kt[3][j].w;
        uint2 w2; w2.x = cvtpk(s0, s1); w2.y = cvtpk(s2, s3);
        *(uint2*)(sGc + swz(ap, ah * 64 + au * 16 + 4 * j)) = w2;   // 8B, aligned
      }
    }
    SB();
    BAR();
  }

  // ---- tail: GEMM2 for the last tile ----
  {
    const unsigned short* sGp = sG + ((NT_ - 1) & 1) * 16384;
    f32x4 a20 = f32x4{0.f, 0.f, 0.f, 0.f};
    f32x4 a21 = f32x4{0.f, 0.f, 0.f, 0.f};
#pragma unroll
    for (int kk = 0; kk < 8; ++kk) {
      short8 af2 = *(const short8*)(sGp + p2g * 256 + (((kk * 4 + q) ^ (p2g & 31)) << 3));
      a20 = __builtin_amdgcn_mfma_f32_16x16x32_bf16(af2, mb0[kk], a20, 0, 0, 0);
      a21 = __builtin_amdgcn_mfma_f32_16x16x32_bf16(af2, mb1[kk], a21, 0, 0, 0);
    }
    const size_t rb = ((size_t)(blockIdx.x + (size_t)(NT_ - 1) * NPB) * PB
                       + (size_t)(mt * 16 + q * 4)) * 128;
#pragma unroll
    for (int r = 0; r < 4; ++r) {
      out[rb + r * 128 + ng * 32 + l]      = a20[r] + bo0;
      out[rb + r * 128 + ng * 32 + 16 + l] = a21[r] + bo1;
    }
  }
}

extern "C" void kernel_launch(void* const* d_in, const int* in_sizes, int n_in,
                              void* d_out, int out_size, void* d_ws, size_t ws_size,
                              hipStream_t stream) {
  const float* z2d = (const float*)d_in[0];
  const float* t2d = (const float*)d_in[1];
  const float* Wq  = (const float*)d_in[2];
  const float* Wk  = (const float*)d_in[3];
  const float* Wv  = (const float*)d_in[4];
  const float* Wo  = (const float*)d_in[5];
  const float* bo  = (const float*)d_in[6];

  unsigned short* AbarT = (unsigned short*)d_ws;           // 256*128 bf16 = 64 KB
  unsigned short* MbarT = AbarT + 256 * 128;               // 128*256 bf16 = 64 KB
  float* out = (float*)d_out;

  static bool attr_set = false;
  if (!attr_set) {
    (void)hipFuncSetAttribute((const void*)attn_kernel,
                              hipFuncAttributeMaxDynamicSharedMemorySize, 131072);
    attr_set = true;
  }

  hipLaunchKernelGGL(prep_kernel, dim3(256), dim3(256), 0, stream,
                     Wq, Wk, Wv, Wo, AbarT, MbarT);
  hipLaunchKernelGGL(attn_kernel, dim3(NPB), dim3(1024), 131072, stream,
                     z2d, t2d, AbarT, MbarT, bo, out);
}